// Round 1
// baseline (3579.964 us; speedup 1.0000x reference)
//
#include <hip/hip_runtime.h>

// ---------------------------------------------------------------------------
// GCN 3-layer forward, all f32.
//   per layer: H = A_in @ W ; AGG = seg_sum(H[src]*norm, dst) + self ; (+b, relu)
// bias+relu fused into the NEXT gemm's A-staging (pre-activation).
// Aggregation: init pass (self-loop + optional bias) + edge-parallel atomics.
// ---------------------------------------------------------------------------

#define DEV_INLINE __device__ __forceinline__

static DEV_INLINE void fma4(float4& acc, float a, const float4& w) {
    acc.x = fmaf(a, w.x, acc.x);
    acc.y = fmaf(a, w.y, acc.y);
    acc.z = fmaf(a, w.z, acc.z);
    acc.w = fmaf(a, w.w, acc.w);
}

// ------------------------- degree / norm precompute -------------------------

__global__ void deg_init_kernel(float* __restrict__ deg, int N) {
    int i = blockIdx.x * blockDim.x + threadIdx.x;
    if (i < N) deg[i] = 1.0f;   // self-loop contributes 1
}

__global__ void deg_accum_kernel(float* __restrict__ deg, const int* __restrict__ dst, int E) {
    int e = blockIdx.x * blockDim.x + threadIdx.x;
    if (e < E) atomicAdd(&deg[dst[e]], 1.0f);
}

__global__ void dinv_kernel(float* __restrict__ deg_inplace, int N) {
    int i = blockIdx.x * blockDim.x + threadIdx.x;
    if (i < N) deg_inplace[i] = rsqrtf(deg_inplace[i]);   // deg >= 1 always
}

__global__ void norm_kernel(const float* __restrict__ dinv,
                            const int* __restrict__ src, const int* __restrict__ dst,
                            float* __restrict__ norm, int E) {
    int e = blockIdx.x * blockDim.x + threadIdx.x;
    if (e < E) norm[e] = dinv[src[e]] * dinv[dst[e]];
}

// --------------------------------- GEMM -------------------------------------
// C[N,NOUT] = preact(A[N,K]) @ W[K,NOUT],  preact = PRE ? relu(a + bias[k]) : a
// block: 256 threads, BM=64 rows; K chunked at KC=64 (<=64KB static LDS).
// per-thread tile: RPT rows x 8 cols (two float4 groups at tx*4 and tx*4+NOUT/2).

template<int K, int NOUT, bool PRE>
__global__ __launch_bounds__(256, 2) void gemm_kernel(
    const float* __restrict__ A, const float* __restrict__ W,
    const float* __restrict__ bias, float* __restrict__ C, int N)
{
    constexpr int BM   = 64;
    constexpr int KC   = 64;           // K-chunk
    constexpr int NCH  = K / KC;       // 1 or 2
    constexpr int COLT = NOUT / 8;     // col-threads (16 or 8)
    constexpr int ROWT = 256 / COLT;   // row-threads (16 or 32)
    constexpr int RPT  = BM / ROWT;    // rows per thread (4 or 2)
    constexpr int LDA  = KC + 4;       // pad: stride%32==4 -> conflict-free

    __shared__ float  As[BM][LDA];
    __shared__ float4 Ws[KC][NOUT / 4];

    const int tid  = threadIdx.x;
    const int row0 = blockIdx.x * BM;
    const int tx   = tid % COLT;
    const int ty   = tid / COLT;

    float4 acc0[RPT], acc1[RPT];
#pragma unroll
    for (int i = 0; i < RPT; ++i) {
        acc0[i] = make_float4(0.f, 0.f, 0.f, 0.f);
        acc1[i] = make_float4(0.f, 0.f, 0.f, 0.f);
    }

    for (int ch = 0; ch < NCH; ++ch) {
        // ---- stage W chunk (contiguous KC*NOUT floats) ----
        {
            const float4* Wg = reinterpret_cast<const float4*>(W + (size_t)ch * KC * NOUT);
            constexpr int TOT = KC * NOUT / 4;
            for (int idx = tid; idx < TOT; idx += 256)
                reinterpret_cast<float4*>(Ws)[idx] = Wg[idx];
        }
        // ---- stage A chunk with fused pre-activation ----
        {
            constexpr int KF  = KC / 4;
            constexpr int TOT = BM * KF;
            const float4* bias4 = reinterpret_cast<const float4*>(bias);
            for (int idx = tid; idx < TOT; idx += 256) {
                int r  = idx / KF;
                int kf = idx % KF;
                int gr = row0 + r;
                float4 v = make_float4(0.f, 0.f, 0.f, 0.f);
                if (gr < N) {
                    v = reinterpret_cast<const float4*>(A + (size_t)gr * K + ch * KC)[kf];
                    if (PRE) {
                        float4 b = bias4[ch * (KC / 4) + kf];
                        v.x = fmaxf(v.x + b.x, 0.f);
                        v.y = fmaxf(v.y + b.y, 0.f);
                        v.z = fmaxf(v.z + b.z, 0.f);
                        v.w = fmaxf(v.w + b.w, 0.f);
                    }
                }
                *reinterpret_cast<float4*>(&As[r][kf * 4]) = v;
            }
        }
        __syncthreads();

        // ---- compute ----
#pragma unroll 4
        for (int k = 0; k < KC; ++k) {
            float4 w0 = Ws[k][tx];
            float4 w1 = Ws[k][tx + NOUT / 8];
#pragma unroll
            for (int i = 0; i < RPT; ++i) {
                float a = As[ty + ROWT * i][k];
                fma4(acc0[i], a, w0);
                fma4(acc1[i], a, w1);
            }
        }
        __syncthreads();
    }

    // ---- store ----
#pragma unroll
    for (int i = 0; i < RPT; ++i) {
        int gr = row0 + ty + ROWT * i;
        if (gr < N) {
            float4* C4 = reinterpret_cast<float4*>(C + (size_t)gr * NOUT);
            C4[tx]            = acc0[i];
            C4[tx + NOUT / 8] = acc1[i];
        }
    }
}

// ------------------------------ aggregation ---------------------------------

// AGG[i,:] = (bias? bias : 0) + H[i,:] * dinv[i]^2      (self-loop term)
template<int F>
__global__ void agg_init_kernel(const float* __restrict__ H, const float* __restrict__ dinv,
                                const float* __restrict__ bias, float* __restrict__ AGG, int N)
{
    constexpr int Q = F / 4;
    int gid = blockIdx.x * blockDim.x + threadIdx.x;
    if (gid >= N * Q) return;
    int node = gid / Q;
    int q    = gid % Q;
    float s  = dinv[node];
    s = s * s;
    float4 h = reinterpret_cast<const float4*>(H)[gid];
    float4 o;
    o.x = h.x * s; o.y = h.y * s; o.z = h.z * s; o.w = h.w * s;
    if (bias != nullptr) {
        float4 b = reinterpret_cast<const float4*>(bias)[q];
        o.x += b.x; o.y += b.y; o.z += b.z; o.w += b.w;
    }
    reinterpret_cast<float4*>(AGG)[gid] = o;
}

// AGG[dst,:] += H[src,:] * norm[e]   (scatter atomics, float4 gather + 4 atomics)
template<int F>
__global__ void agg_edges_kernel(const float* __restrict__ H, float* __restrict__ AGG,
                                 const int* __restrict__ src, const int* __restrict__ dst,
                                 const float* __restrict__ norm, int E)
{
    constexpr int Q = F / 4;
    int gid = blockIdx.x * blockDim.x + threadIdx.x;
    if (gid >= E * Q) return;
    int e = gid / Q;
    int q = gid % Q;
    int s = src[e];
    int d = dst[e];
    float n  = norm[e];
    float4 h = reinterpret_cast<const float4*>(H + (size_t)s * F)[q];
    float* out = AGG + (size_t)d * F + q * 4;
    atomicAdd(out + 0, h.x * n);
    atomicAdd(out + 1, h.y * n);
    atomicAdd(out + 2, h.z * n);
    atomicAdd(out + 3, h.w * n);
}

// ------------------------------- launcher -----------------------------------

static inline size_t align_up(size_t v, size_t a) { return (v + a - 1) / a * a; }

extern "C" void kernel_launch(void* const* d_in, const int* in_sizes, int n_in,
                              void* d_out, int out_size, void* d_ws, size_t ws_size,
                              hipStream_t stream) {
    const float* x  = (const float*)d_in[0];
    const int*   ei = (const int*)d_in[1];
    const float* W1 = (const float*)d_in[2];
    const float* b1 = (const float*)d_in[3];
    const float* W2 = (const float*)d_in[4];
    const float* b2 = (const float*)d_in[5];
    const float* W3 = (const float*)d_in[6];
    const float* b3 = (const float*)d_in[7];
    float* out = (float*)d_out;

    const int N = in_sizes[0] / 128;   // 50000
    const int E = in_sizes[1] / 2;     // 800000
    const int* src = ei;
    const int* dst = ei + E;

    // workspace layout (all 512B aligned)
    char* ws = (char*)d_ws;
    size_t off = 0;
    float* dinv = (float*)(ws + off); off = align_up(off + (size_t)N * 4, 512);
    float* nrm  = (float*)(ws + off); off = align_up(off + (size_t)E * 4, 512);
    float* H    = (float*)(ws + off); off = align_up(off + (size_t)N * 128 * 4, 512);
    float* AGG  = (float*)(ws + off); off = align_up(off + (size_t)N * 128 * 4, 512);
    (void)ws_size;

    const int TPB = 256;
    dim3 blk(TPB);
    int gN   = (N + TPB - 1) / TPB;
    int gE   = (E + TPB - 1) / TPB;
    int gRow = (N + 63) / 64;

    // degree / dinv / norm (reused by all 3 layers)
    deg_init_kernel<<<gN, blk, 0, stream>>>(dinv, N);
    deg_accum_kernel<<<gE, blk, 0, stream>>>(dinv, dst, E);
    dinv_kernel<<<gN, blk, 0, stream>>>(dinv, N);
    norm_kernel<<<gE, blk, 0, stream>>>(dinv, src, dst, nrm, E);

    // ---- layer 1: H1 = x @ W1 ; AGG1 = seg(H1) ----
    gemm_kernel<128, 128, false><<<gRow, blk, 0, stream>>>(x, W1, nullptr, H, N);
    agg_init_kernel<128><<<(N * 32 + TPB - 1) / TPB, blk, 0, stream>>>(H, dinv, nullptr, AGG, N);
    agg_edges_kernel<128><<<(E * 32 + TPB - 1) / TPB, blk, 0, stream>>>(H, AGG, src, dst, nrm, E);

    // ---- layer 2: H2 = relu(AGG1 + b1) @ W2 ; AGG2 = seg(H2) ----
    gemm_kernel<128, 64, true><<<gRow, blk, 0, stream>>>(AGG, W2, b1, H, N);
    agg_init_kernel<64><<<(N * 16 + TPB - 1) / TPB, blk, 0, stream>>>(H, dinv, nullptr, AGG, N);
    agg_edges_kernel<64><<<(E * 16 + TPB - 1) / TPB, blk, 0, stream>>>(H, AGG, src, dst, nrm, E);

    // ---- layer 3: H3 = relu(AGG2 + b2) @ W3 ; out = seg(H3) + b3 ----
    gemm_kernel<64, 128, true><<<gRow, blk, 0, stream>>>(AGG, W3, b2, H, N);
    agg_init_kernel<128><<<(N * 32 + TPB - 1) / TPB, blk, 0, stream>>>(H, dinv, b3, out, N);
    agg_edges_kernel<128><<<(E * 32 + TPB - 1) / TPB, blk, 0, stream>>>(H, out, src, dst, nrm, E);
}

// Round 2
// 353.900 us; speedup vs baseline: 10.1157x; 10.1157x over previous
//
#include <hip/hip_runtime.h>

// ---------------------------------------------------------------------------
// GCN 3-layer forward, all f32. CSR-gather aggregation (no float atomics).
//
// Per call:
//   1. count in-degrees (int atomics) -> block-scan -> rowptr/cursor
//   2. counting-sort edges by dst -> perm_src (uint16, N<65536)
//   3. layer 1: H1 = x@W1            ; AGG1 = Ahat(H1)
//      layer 2: H2 = relu(AGG1+b1)@W2; H3   = relu(Ahat(H2)+b2)
//      layer 3: T  = Ahat(H3)        ; out  = T@W3 + b3     [Ahat(HW)=(AhatH)W]
//   norm recomputed on the fly: norm(s,d) = dinv[s]*dinv[d].
// ---------------------------------------------------------------------------

#define DEV_INLINE __device__ __forceinline__

static DEV_INLINE void fma4(float4& acc, float a, const float4& w) {
    acc.x = fmaf(a, w.x, acc.x);
    acc.y = fmaf(a, w.y, acc.y);
    acc.z = fmaf(a, w.z, acc.z);
    acc.w = fmaf(a, w.w, acc.w);
}

// ------------------------------ CSR build -----------------------------------

__global__ void zero_int_kernel(int* __restrict__ p, int N) {
    int i = blockIdx.x * blockDim.x + threadIdx.x;
    if (i < N) p[i] = 0;
}

__global__ void count_edges_kernel(int* __restrict__ cnt, const int* __restrict__ dst, int E) {
    int e = blockIdx.x * blockDim.x + threadIdx.x;
    if (e < E) atomicAdd(&cnt[dst[e]], 1);
}

// per-block exclusive scan of cnt -> rowptr(local); block totals -> bsum; dinv
__global__ void scan_block_kernel(const int* __restrict__ cnt, int* __restrict__ rowptr,
                                  int* __restrict__ bsum, float* __restrict__ dinv, int N) {
    __shared__ int buf[256];
    const int tid = threadIdx.x;
    const int i   = blockIdx.x * 256 + tid;
    int v = (i < N) ? cnt[i] : 0;
    if (i < N) dinv[i] = rsqrtf((float)(v + 1));   // +1 self-loop
    buf[tid] = v;
    __syncthreads();
#pragma unroll
    for (int ofs = 1; ofs < 256; ofs <<= 1) {
        int t = (tid >= ofs) ? buf[tid - ofs] : 0;
        __syncthreads();
        buf[tid] += t;
        __syncthreads();
    }
    if (i < N) rowptr[i] = buf[tid] - v;           // exclusive within block
    if (tid == 255) bsum[blockIdx.x] = buf[255];
}

// single-block exclusive scan of bsum (NB <= 256)
__global__ void scan_bsum_kernel(const int* __restrict__ bsum, int* __restrict__ bpref, int NB) {
    __shared__ int buf[256];
    const int tid = threadIdx.x;
    int v = (tid < NB) ? bsum[tid] : 0;
    buf[tid] = v;
    __syncthreads();
#pragma unroll
    for (int ofs = 1; ofs < 256; ofs <<= 1) {
        int t = (tid >= ofs) ? buf[tid - ofs] : 0;
        __syncthreads();
        buf[tid] += t;
        __syncthreads();
    }
    if (tid < NB) bpref[tid] = buf[tid] - v;
}

__global__ void finalize_rowptr_kernel(int* __restrict__ rowptr, int* __restrict__ cursor,
                                       const int* __restrict__ bpref, int N, int E) {
    int i = blockIdx.x * blockDim.x + threadIdx.x;
    if (i < N) {
        int r = rowptr[i] + bpref[i >> 8];
        rowptr[i] = r;
        cursor[i] = r;
    }
    if (i == 0) rowptr[N] = E;
}

__global__ void scatter_edges_kernel(const int* __restrict__ src, const int* __restrict__ dst,
                                     int* __restrict__ cursor,
                                     unsigned short* __restrict__ perm_src, int E) {
    int e = blockIdx.x * blockDim.x + threadIdx.x;
    if (e >= E) return;
    int d = dst[e];
    int pos = atomicAdd(&cursor[d], 1);
    perm_src[pos] = (unsigned short)src[e];
}

// --------------------------------- GEMM -------------------------------------
// C[N,NOUT] = preact(A[N,K]) @ W[K,NOUT] (+ bias if POSTB)
//   preact = PRE ? relu(a + bias[k]) : a
// block: 256 threads, BM=64 rows; K chunked at KC=64.

template<int K, int NOUT, bool PRE, bool POSTB>
__global__ __launch_bounds__(256, 2) void gemm_kernel(
    const float* __restrict__ A, const float* __restrict__ W,
    const float* __restrict__ bias, float* __restrict__ C, int N)
{
    constexpr int BM   = 64;
    constexpr int KC   = 64;
    constexpr int NCH  = K / KC;
    constexpr int COLT = NOUT / 8;
    constexpr int ROWT = 256 / COLT;
    constexpr int RPT  = BM / ROWT;
    constexpr int LDA  = KC + 4;

    __shared__ float  As[BM][LDA];
    __shared__ float4 Ws[KC][NOUT / 4];

    const int tid  = threadIdx.x;
    const int row0 = blockIdx.x * BM;
    const int tx   = tid % COLT;
    const int ty   = tid / COLT;

    float4 acc0[RPT], acc1[RPT];
#pragma unroll
    for (int i = 0; i < RPT; ++i) {
        acc0[i] = make_float4(0.f, 0.f, 0.f, 0.f);
        acc1[i] = make_float4(0.f, 0.f, 0.f, 0.f);
    }

    for (int ch = 0; ch < NCH; ++ch) {
        {
            const float4* Wg = reinterpret_cast<const float4*>(W + (size_t)ch * KC * NOUT);
            constexpr int TOT = KC * NOUT / 4;
            for (int idx = tid; idx < TOT; idx += 256)
                reinterpret_cast<float4*>(Ws)[idx] = Wg[idx];
        }
        {
            constexpr int KF  = KC / 4;
            constexpr int TOT = BM * KF;
            const float4* bias4 = reinterpret_cast<const float4*>(bias);
            for (int idx = tid; idx < TOT; idx += 256) {
                int r  = idx / KF;
                int kf = idx % KF;
                int gr = row0 + r;
                float4 v = make_float4(0.f, 0.f, 0.f, 0.f);
                if (gr < N) {
                    v = reinterpret_cast<const float4*>(A + (size_t)gr * K + ch * KC)[kf];
                    if (PRE) {
                        float4 b = bias4[ch * (KC / 4) + kf];
                        v.x = fmaxf(v.x + b.x, 0.f);
                        v.y = fmaxf(v.y + b.y, 0.f);
                        v.z = fmaxf(v.z + b.z, 0.f);
                        v.w = fmaxf(v.w + b.w, 0.f);
                    }
                }
                *reinterpret_cast<float4*>(&As[r][kf * 4]) = v;
            }
        }
        __syncthreads();

#pragma unroll 4
        for (int k = 0; k < KC; ++k) {
            float4 w0 = Ws[k][tx];
            float4 w1 = Ws[k][tx + NOUT / 8];
#pragma unroll
            for (int i = 0; i < RPT; ++i) {
                float a = As[ty + ROWT * i][k];
                fma4(acc0[i], a, w0);
                fma4(acc1[i], a, w1);
            }
        }
        __syncthreads();
    }

    if (POSTB) {
        const float4* bias4 = reinterpret_cast<const float4*>(bias);
        float4 pb0 = bias4[tx];
        float4 pb1 = bias4[tx + NOUT / 8];
#pragma unroll
        for (int i = 0; i < RPT; ++i) {
            acc0[i].x += pb0.x; acc0[i].y += pb0.y; acc0[i].z += pb0.z; acc0[i].w += pb0.w;
            acc1[i].x += pb1.x; acc1[i].y += pb1.y; acc1[i].z += pb1.z; acc1[i].w += pb1.w;
        }
    }

#pragma unroll
    for (int i = 0; i < RPT; ++i) {
        int gr = row0 + ty + ROWT * i;
        if (gr < N) {
            float4* C4 = reinterpret_cast<float4*>(C + (size_t)gr * NOUT);
            C4[tx]            = acc0[i];
            C4[tx + NOUT / 8] = acc1[i];
        }
    }
}

// ------------------------------ aggregation ---------------------------------
// OUT[i,:] = opt_relu( sum_{e in in(i)} H[src_e,:]*dinv[src_e]*dinv[i]
//                      + H[i,:]*dinv[i]^2 + opt_bias )
// GROUP = F/4 threads per node, float4 per lane.

template<int F, bool BIAS, bool RELU>
__global__ __launch_bounds__(256) void agg_gather_kernel(
    const float* __restrict__ H, const int* __restrict__ rowptr,
    const unsigned short* __restrict__ perm_src, const float* __restrict__ dinv,
    const float* __restrict__ bias, float* __restrict__ OUT, int N)
{
    constexpr int GROUP = F / 4;
    constexpr int NPB   = 256 / GROUP;
    const int lane = threadIdx.x % GROUP;
    const int g    = threadIdx.x / GROUP;
    const int node = blockIdx.x * NPB + g;
    if (node >= N) return;

    const int beg = rowptr[node];
    const int end = rowptr[node + 1];
    const float di = dinv[node];

    // self-loop term
    float4 h0 = reinterpret_cast<const float4*>(H + (size_t)node * F)[lane];
    float  ds = di * di;
    float4 acc  = make_float4(h0.x * ds, h0.y * ds, h0.z * ds, h0.w * ds);
    float4 acc2 = make_float4(0.f, 0.f, 0.f, 0.f);

    int e = beg;
    for (; e + 1 < end; e += 2) {
        int s0 = perm_src[e];
        int s1 = perm_src[e + 1];
        float n0 = dinv[s0] * di;
        float n1 = dinv[s1] * di;
        float4 a = reinterpret_cast<const float4*>(H + (size_t)s0 * F)[lane];
        float4 b = reinterpret_cast<const float4*>(H + (size_t)s1 * F)[lane];
        fma4(acc,  n0, a);
        fma4(acc2, n1, b);
    }
    if (e < end) {
        int s0 = perm_src[e];
        float n0 = dinv[s0] * di;
        float4 a = reinterpret_cast<const float4*>(H + (size_t)s0 * F)[lane];
        fma4(acc, n0, a);
    }
    acc.x += acc2.x; acc.y += acc2.y; acc.z += acc2.z; acc.w += acc2.w;

    if (BIAS) {
        float4 b = reinterpret_cast<const float4*>(bias)[lane];
        acc.x += b.x; acc.y += b.y; acc.z += b.z; acc.w += b.w;
    }
    if (RELU) {
        acc.x = fmaxf(acc.x, 0.f); acc.y = fmaxf(acc.y, 0.f);
        acc.z = fmaxf(acc.z, 0.f); acc.w = fmaxf(acc.w, 0.f);
    }
    reinterpret_cast<float4*>(OUT + (size_t)node * F)[lane] = acc;
}

// ------------------------------- launcher -----------------------------------

static inline size_t align_up(size_t v, size_t a) { return (v + a - 1) / a * a; }

extern "C" void kernel_launch(void* const* d_in, const int* in_sizes, int n_in,
                              void* d_out, int out_size, void* d_ws, size_t ws_size,
                              hipStream_t stream) {
    const float* x  = (const float*)d_in[0];
    const int*   ei = (const int*)d_in[1];
    const float* W1 = (const float*)d_in[2];
    const float* b1 = (const float*)d_in[3];
    const float* W2 = (const float*)d_in[4];
    const float* b2 = (const float*)d_in[5];
    const float* W3 = (const float*)d_in[6];
    const float* b3 = (const float*)d_in[7];
    float* out = (float*)d_out;

    const int N = in_sizes[0] / 128;   // 50000
    const int E = in_sizes[1] / 2;     // 800000
    const int* src = ei;
    const int* dst = ei + E;
    const int NB = (N + 255) / 256;    // scan blocks (196 <= 256)

    // workspace layout
    char* ws = (char*)d_ws;
    size_t off = 0;
    float* dinv   = (float*)(ws + off); off = align_up(off + (size_t)N * 4, 512);
    int*   rowptr = (int*)  (ws + off); off = align_up(off + (size_t)(N + 1) * 4, 512);
    int*   cursor = (int*)  (ws + off); off = align_up(off + (size_t)N * 4, 512);
    int*   bsum   = (int*)  (ws + off); off = align_up(off + (size_t)NB * 4, 512);
    int*   bpref  = (int*)  (ws + off); off = align_up(off + (size_t)NB * 4, 512);
    unsigned short* perm_src = (unsigned short*)(ws + off); off = align_up(off + (size_t)E * 2, 512);
    float* H      = (float*)(ws + off); off = align_up(off + (size_t)N * 128 * 4, 512);
    float* AGG    = (float*)(ws + off); off = align_up(off + (size_t)N * 128 * 4, 512);
    (void)ws_size;

    const int TPB = 256;
    dim3 blk(TPB);
    int gN   = (N + TPB - 1) / TPB;
    int gE   = (E + TPB - 1) / TPB;
    int gRow = (N + 63) / 64;

    // ---- CSR build (reused by all layers) ----
    zero_int_kernel<<<gN, blk, 0, stream>>>(cursor, N);
    count_edges_kernel<<<gE, blk, 0, stream>>>(cursor, dst, E);
    scan_block_kernel<<<NB, blk, 0, stream>>>(cursor, rowptr, bsum, dinv, N);
    scan_bsum_kernel<<<1, blk, 0, stream>>>(bsum, bpref, NB);
    finalize_rowptr_kernel<<<gN, blk, 0, stream>>>(rowptr, cursor, bpref, N, E);
    scatter_edges_kernel<<<gE, blk, 0, stream>>>(src, dst, cursor, perm_src, E);

    // ---- layer 1: H1 = x@W1 ; AGG1 = Ahat(H1) ----
    gemm_kernel<128, 128, false, false><<<gRow, blk, 0, stream>>>(x, W1, nullptr, H, N);
    agg_gather_kernel<128, false, false><<<(N + 7) / 8, blk, 0, stream>>>(
        H, rowptr, perm_src, dinv, nullptr, AGG, N);

    // ---- layer 2: H2 = relu(AGG1+b1)@W2 ; H3 = relu(Ahat(H2)+b2) ----
    gemm_kernel<128, 64, true, false><<<gRow, blk, 0, stream>>>(AGG, W2, b1, H, N);
    agg_gather_kernel<64, true, true><<<(N + 15) / 16, blk, 0, stream>>>(
        H, rowptr, perm_src, dinv, b2, AGG, N);

    // ---- layer 3: T = Ahat(H3) ; out = T@W3 + b3 ----
    agg_gather_kernel<64, false, false><<<(N + 15) / 16, blk, 0, stream>>>(
        AGG, rowptr, perm_src, dinv, nullptr, H, N);
    gemm_kernel<64, 128, false, true><<<gRow, blk, 0, stream>>>(H, W3, b3, out, N);
}